// Round 1
// baseline (3909.666 us; speedup 1.0000x reference)
//
#include <hip/hip_runtime.h>

// Problem constants (fixed by the reference setup_inputs)
#define GRID_D 20
#define RVOX   8000       // 20*20*20
#define BDIM   16
#define CDIM   64
#define NPTS   65536

// Phase 1: scatter-add features into per-voxel sums (in d_out) and per-voxel
// counts (in d_ws). Thread-per-point: feature reads are fully coalesced
// (lane i reads features[b][c][n0+i], consecutive addresses per wave).
__global__ __launch_bounds__(256) void voxel_scatter(
    const float* __restrict__ features,   // [B, C, N]
    const float* __restrict__ coords,     // [B, N, 3]
    const float* __restrict__ search_area,// [B, 3]
    float* __restrict__ sums,             // [B, C, R]  (accumulated in d_out)
    float* __restrict__ counts)           // [B, R]     (in d_ws)
{
    int gid = blockIdx.x * blockDim.x + threadIdx.x;   // 0 .. B*N-1
    int b = gid >> 16;          // N = 65536
    int n = gid & (NPTS - 1);

    // voxel size = search_area / 20
    const float inv_grid = 1.0f / (float)GRID_D;
    float vsx = search_area[b * 3 + 0] * inv_grid;
    float vsy = search_area[b * 3 + 1] * inv_grid;
    float vsz = search_area[b * 3 + 2] * inv_grid;

    const float* cp = coords + (size_t)b * NPTS * 3 + (size_t)n * 3;
    float cx = cp[0], cy = cp[1], cz = cp[2];

    int ix = (int)(floorf(cx / vsx) + 10.0f);
    int iy = (int)(floorf(cy / vsy) + 10.0f);
    int iz = (int)(floorf(cz / vsz) + 10.0f);
    ix = min(max(ix, 0), GRID_D - 1);
    iy = min(max(iy, 0), GRID_D - 1);
    iz = min(max(iz, 0), GRID_D - 1);
    int flat = ix * (GRID_D * GRID_D) + iy * GRID_D + iz;

    atomicAdd(&counts[b * RVOX + flat], 1.0f);

    const float* fbase = features + (size_t)b * CDIM * NPTS + n;
    float* obase = sums + (size_t)b * CDIM * RVOX + flat;
#pragma unroll 8
    for (int c = 0; c < CDIM; ++c) {
        atomicAdd(obase + (size_t)c * RVOX, fbase[(size_t)c * NPTS]);
    }
}

// Phase 2: divide sums by max(count,1). float4-vectorized: R=8000 and C*R are
// multiples of 4, so each float4 of the output lies within one (b,c) row and
// the matching counts are a contiguous aligned float4.
__global__ __launch_bounds__(256) void voxel_finalize(
    float* __restrict__ out,              // [B, C, R]
    const float* __restrict__ counts)     // [B, R]
{
    int gid = blockIdx.x * blockDim.x + threadIdx.x;   // 0 .. B*C*R/4-1
    int i = gid * 4;
    int b = i / (CDIM * RVOX);
    int r = i % RVOX;

    float4 s = reinterpret_cast<float4*>(out)[gid];
    float4 cnt = reinterpret_cast<const float4*>(counts)[(b * RVOX + r) >> 2];

    s.x = s.x / fmaxf(cnt.x, 1.0f);
    s.y = s.y / fmaxf(cnt.y, 1.0f);
    s.z = s.z / fmaxf(cnt.z, 1.0f);
    s.w = s.w / fmaxf(cnt.w, 1.0f);

    reinterpret_cast<float4*>(out)[gid] = s;
}

extern "C" void kernel_launch(void* const* d_in, const int* in_sizes, int n_in,
                              void* d_out, int out_size, void* d_ws, size_t ws_size,
                              hipStream_t stream) {
    const float* features    = (const float*)d_in[0];  // [16, 64, 65536]
    const float* coords      = (const float*)d_in[1];  // [16, 65536, 3]
    const float* search_area = (const float*)d_in[2];  // [16, 3]
    float* out = (float*)d_out;                        // [16, 64, 8000]
    float* counts = (float*)d_ws;                      // [16, 8000]

    // d_out / d_ws are poisoned to 0xAA before every call — zero them.
    hipMemsetAsync(out, 0, (size_t)out_size * sizeof(float), stream);
    hipMemsetAsync(counts, 0, (size_t)BDIM * RVOX * sizeof(float), stream);

    // Scatter: one thread per point.
    int npoints = BDIM * NPTS;                 // 1,048,576
    voxel_scatter<<<npoints / 256, 256, 0, stream>>>(
        features, coords, search_area, out, counts);

    // Finalize: float4 over B*C*R elements.
    int nvec = (BDIM * CDIM * RVOX) / 4;       // 2,048,000
    voxel_finalize<<<(nvec + 255) / 256, 256, 0, stream>>>(out, counts);
}

// Round 2
// 1669.330 us; speedup vs baseline: 2.3421x; 2.3421x over previous
//
#include <hip/hip_runtime.h>

// Problem constants (fixed by the reference setup_inputs)
#define GRID_D 20
#define RVOX   8000                 // 20^3
#define BDIM   16
#define CDIM   64
#define NPTS   65536
#define NSEG   (BDIM * RVOX)        // 128000 segments
#define NPT_TOT (BDIM * NPTS)       // 1048576 points
#define SCAN_T 256
#define SCAN_NB (NSEG / SCAN_T)     // 500 blocks (exact)
#define CG     4                    // channel groups in gather
#define CPG    (CDIM / CG)          // 16 channels per thread

// ---------- shared helper: voxel index (identical math to verified R1) ------
__device__ __forceinline__ int voxel_seg(const float* __restrict__ coords,
                                         const float* __restrict__ search_area,
                                         int b, int n) {
    const float inv_grid = 1.0f / (float)GRID_D;
    float vsx = search_area[b * 3 + 0] * inv_grid;
    float vsy = search_area[b * 3 + 1] * inv_grid;
    float vsz = search_area[b * 3 + 2] * inv_grid;
    const float* cp = coords + (size_t)b * NPTS * 3 + (size_t)n * 3;
    float cx = cp[0], cy = cp[1], cz = cp[2];
    int ix = (int)(floorf(cx / vsx) + 10.0f);
    int iy = (int)(floorf(cy / vsy) + 10.0f);
    int iz = (int)(floorf(cz / vsz) + 10.0f);
    ix = min(max(ix, 0), GRID_D - 1);
    iy = min(max(iy, 0), GRID_D - 1);
    iz = min(max(iz, 0), GRID_D - 1);
    return b * RVOX + ix * (GRID_D * GRID_D) + iy * GRID_D + iz;
}

// ---------- CSR path --------------------------------------------------------
// Phase 1: per-point segment id + int histogram (L2-resident 512 KB array).
__global__ __launch_bounds__(256) void k_hist(
    const float* __restrict__ coords, const float* __restrict__ search_area,
    int* __restrict__ seg_idx, int* __restrict__ hist)
{
    int gid = blockIdx.x * 256 + threadIdx.x;     // 0 .. NPT_TOT-1
    int b = gid >> 16;
    int n = gid & (NPTS - 1);
    int seg = voxel_seg(coords, search_area, b, n);
    seg_idx[gid] = seg;
    atomicAdd(&hist[seg], 1);
}

// Phase 2a: per-block exclusive scan (256-chunk), emit block sums.
__global__ __launch_bounds__(SCAN_T) void k_scan1(
    const int* __restrict__ hist, int* __restrict__ offs, int* __restrict__ bsum)
{
    __shared__ int s[SCAN_T];
    int t = threadIdx.x;
    int i = blockIdx.x * SCAN_T + t;
    int x = hist[i];
    s[t] = x;
    __syncthreads();
    for (int off = 1; off < SCAN_T; off <<= 1) {
        int v = 0;
        if (t >= off) v = s[t - off];
        __syncthreads();
        if (t >= off) s[t] += v;
        __syncthreads();
    }
    offs[i] = s[t] - x;                    // local exclusive prefix
    if (t == SCAN_T - 1) bsum[blockIdx.x] = s[t];
}

// Phase 2b: single-block exclusive scan of the 500 block sums.
__global__ __launch_bounds__(512) void k_scan2(
    const int* __restrict__ bsum, int* __restrict__ bpre)
{
    __shared__ int s[512];
    int t = threadIdx.x;
    int x = (t < SCAN_NB) ? bsum[t] : 0;
    s[t] = x;
    __syncthreads();
    for (int off = 1; off < 512; off <<= 1) {
        int v = 0;
        if (t >= off) v = s[t - off];
        __syncthreads();
        if (t >= off) s[t] += v;
        __syncthreads();
    }
    if (t < SCAN_NB) bpre[t] = s[t] - x;   // exclusive prefix of block sums
}

// Phase 2c: add block prefixes -> final offsets; init cursors.
__global__ __launch_bounds__(SCAN_T) void k_scan3(
    int* __restrict__ offs, const int* __restrict__ bpre, int* __restrict__ curs)
{
    int i = blockIdx.x * SCAN_T + threadIdx.x;
    int v = offs[i] + bpre[blockIdx.x];
    offs[i] = v;
    curs[i] = v;
}

// Phase 3: scatter point indices into CSR lists.
__global__ __launch_bounds__(256) void k_fill(
    const int* __restrict__ seg_idx, int* __restrict__ curs, int* __restrict__ plist)
{
    int gid = blockIdx.x * 256 + threadIdx.x;
    int n = gid & (NPTS - 1);
    int pos = atomicAdd(&curs[seg_idx[gid]], 1);
    plist[pos] = n;
}

// Phase 4: gather + mean. Thread = (b, cgroup, r). Writes fully coalesced
// (lanes = consecutive r); gathers are random-n scalar loads, L2/L3-resident
// (one 256KB feature plane per (b,c)). Divide fused; every output written,
// so no d_out zeroing.
__global__ __launch_bounds__(256) void k_gather(
    const float* __restrict__ features, const int* __restrict__ plist,
    const int* __restrict__ offs, const int* __restrict__ hist,
    float* __restrict__ out)
{
    int r = blockIdx.x * 256 + threadIdx.x;
    if (r >= RVOX) return;
    int cg = blockIdx.y;
    int b  = blockIdx.z;
    int seg = b * RVOX + r;
    int k = hist[seg];
    int o = offs[seg];

    float acc[CPG];
#pragma unroll
    for (int t = 0; t < CPG; ++t) acc[t] = 0.0f;

    const float* fb = features + ((size_t)(b * CDIM + cg * CPG)) * NPTS;
    for (int j = 0; j < k; ++j) {
        int n = plist[o + j];
#pragma unroll
        for (int t = 0; t < CPG; ++t)
            acc[t] += fb[(size_t)t * NPTS + n];
    }

    float inv = 1.0f / fmaxf((float)k, 1.0f);
    float* ob = out + ((size_t)(b * CDIM + cg * CPG)) * RVOX + r;
#pragma unroll
    for (int t = 0; t < CPG; ++t)
        ob[(size_t)t * RVOX] = acc[t] * inv;
}

// ---------- legacy fallback (verified R1) — used only if ws too small -------
__global__ __launch_bounds__(256) void voxel_scatter(
    const float* __restrict__ features, const float* __restrict__ coords,
    const float* __restrict__ search_area, float* __restrict__ sums,
    float* __restrict__ counts)
{
    int gid = blockIdx.x * blockDim.x + threadIdx.x;
    int b = gid >> 16;
    int n = gid & (NPTS - 1);
    int seg = voxel_seg(coords, search_area, b, n);
    int flat = seg - b * RVOX;
    atomicAdd(&counts[seg], 1.0f);
    const float* fbase = features + (size_t)b * CDIM * NPTS + n;
    float* obase = sums + (size_t)b * CDIM * RVOX + flat;
#pragma unroll 8
    for (int c = 0; c < CDIM; ++c)
        atomicAdd(obase + (size_t)c * RVOX, fbase[(size_t)c * NPTS]);
}

__global__ __launch_bounds__(256) void voxel_finalize(
    float* __restrict__ out, const float* __restrict__ counts)
{
    int gid = blockIdx.x * blockDim.x + threadIdx.x;
    int i = gid * 4;
    int b = i / (CDIM * RVOX);
    int r = i % RVOX;
    float4 s = reinterpret_cast<float4*>(out)[gid];
    float4 cnt = reinterpret_cast<const float4*>(counts)[(b * RVOX + r) >> 2];
    s.x = s.x / fmaxf(cnt.x, 1.0f);
    s.y = s.y / fmaxf(cnt.y, 1.0f);
    s.z = s.z / fmaxf(cnt.z, 1.0f);
    s.w = s.w / fmaxf(cnt.w, 1.0f);
    reinterpret_cast<float4*>(out)[gid] = s;
}

// ---------- launch ----------------------------------------------------------
extern "C" void kernel_launch(void* const* d_in, const int* in_sizes, int n_in,
                              void* d_out, int out_size, void* d_ws, size_t ws_size,
                              hipStream_t stream) {
    const float* features    = (const float*)d_in[0];  // [16, 64, 65536]
    const float* coords      = (const float*)d_in[1];  // [16, 65536, 3]
    const float* search_area = (const float*)d_in[2];  // [16, 3]
    float* out = (float*)d_out;                        // [16, 64, 8000]

    // Workspace layout (CSR path):
    //   seg_idx: int[NPT_TOT]   @ 0        (4 MB)
    //   plist:   int[NPT_TOT]   @ 4 MB     (4 MB)
    //   hist:    int[NSEG]      @ 8 MB     (500 KB)
    //   offs:    int[NSEG]                 (500 KB)
    //   curs:    int[NSEG]                 (500 KB)
    //   bsum:    int[512]
    //   bpre:    int[512]
    char* w = (char*)d_ws;
    int* seg_idx = (int*)(w);
    int* plist   = (int*)(w + (size_t)NPT_TOT * 4);
    int* hist    = (int*)(w + (size_t)NPT_TOT * 8);
    int* offs    = hist + NSEG;
    int* curs    = offs + NSEG;
    int* bsum    = curs + NSEG;
    int* bpre    = bsum + 512;
    size_t need = (size_t)NPT_TOT * 8 + (size_t)NSEG * 12 + 4096;

    if (ws_size >= need) {
        // CSR path: no fp32 atomics anywhere.
        hipMemsetAsync(hist, 0, (size_t)NSEG * sizeof(int), stream);
        k_hist <<<NPT_TOT / 256, 256, 0, stream>>>(coords, search_area, seg_idx, hist);
        k_scan1<<<SCAN_NB, SCAN_T, 0, stream>>>(hist, offs, bsum);
        k_scan2<<<1, 512, 0, stream>>>(bsum, bpre);
        k_scan3<<<SCAN_NB, SCAN_T, 0, stream>>>(offs, bpre, curs);
        k_fill <<<NPT_TOT / 256, 256, 0, stream>>>(seg_idx, curs, plist);
        dim3 ggrid((RVOX + 255) / 256, CG, BDIM);   // (32, 4, 16)
        k_gather<<<ggrid, 256, 0, stream>>>(features, plist, offs, hist, out);
    } else {
        // Fallback: verified R1 atomic path (needs only 512 KB ws).
        float* counts = (float*)d_ws;
        hipMemsetAsync(out, 0, (size_t)out_size * sizeof(float), stream);
        hipMemsetAsync(counts, 0, (size_t)NSEG * sizeof(float), stream);
        voxel_scatter<<<NPT_TOT / 256, 256, 0, stream>>>(
            features, coords, search_area, out, counts);
        int nvec = (BDIM * CDIM * RVOX) / 4;
        voxel_finalize<<<(nvec + 255) / 256, 256, 0, stream>>>(out, counts);
    }
}

// Round 3
// 679.971 us; speedup vs baseline: 5.7498x; 2.4550x over previous
//
#include <hip/hip_runtime.h>

// Problem constants (fixed by the reference setup_inputs)
#define GRID_D 20
#define RVOX   8000                 // 20^3
#define BDIM   16
#define CDIM   64
#define NPTS   65536
#define NSEG   (BDIM * RVOX)        // 128000
#define NPT_TOT (BDIM * NPTS)       // 1048576
#define CH     2                    // channels per accumulation block (LDS = CH*RVOX*4 = 64 KB)

// ---------- Phase 1: per-point voxel id (u16) + int histogram ---------------
// Same index math as the verified R1/R2 kernels.
__global__ __launch_bounds__(256) void k_seg(
    const float* __restrict__ coords, const float* __restrict__ search_area,
    unsigned short* __restrict__ seg_idx, int* __restrict__ hist)
{
    int gid = blockIdx.x * 256 + threadIdx.x;     // 0 .. NPT_TOT-1
    int b = gid >> 16;
    int n = gid & (NPTS - 1);

    const float inv_grid = 1.0f / (float)GRID_D;
    float vsx = search_area[b * 3 + 0] * inv_grid;
    float vsy = search_area[b * 3 + 1] * inv_grid;
    float vsz = search_area[b * 3 + 2] * inv_grid;
    const float* cp = coords + (size_t)b * NPTS * 3 + (size_t)n * 3;
    int ix = (int)(floorf(cp[0] / vsx) + 10.0f);
    int iy = (int)(floorf(cp[1] / vsy) + 10.0f);
    int iz = (int)(floorf(cp[2] / vsz) + 10.0f);
    ix = min(max(ix, 0), GRID_D - 1);
    iy = min(max(iy, 0), GRID_D - 1);
    iz = min(max(iz, 0), GRID_D - 1);
    int seg = ix * (GRID_D * GRID_D) + iy * GRID_D + iz;   // 0..7999

    seg_idx[gid] = (unsigned short)seg;
    atomicAdd(&hist[b * RVOX + seg], 1);          // 512 KB array, L2-resident
}

// ---------- Phase 2: LDS-accumulated segment mean ---------------------------
// Block = (cgroup, b): owns CH channels of one batch element. Streams all
// 65536 points with coalesced float4 feature loads + ushort4 seg ids,
// atomicAdd into LDS sums, then writes out coalesced with the divide fused.
// No global fp32 atomics, features read exactly once.
__global__ __launch_bounds__(256) void k_accum(
    const float* __restrict__ features,           // [B, C, N]
    const unsigned short* __restrict__ seg_idx,   // [B, N]
    const int* __restrict__ hist,                 // [B, R]
    float* __restrict__ out)                      // [B, C, R]
{
    __shared__ float s[CH * RVOX];                // 64 KB -> 2 blocks/CU
    int tid = threadIdx.x;
    int cg = blockIdx.x;                          // 0 .. CDIM/CH-1
    int b  = blockIdx.y;                          // 0 .. BDIM-1

    for (int i = tid; i < CH * RVOX; i += 256) s[i] = 0.0f;
    __syncthreads();

    const float* f0 = features + ((size_t)(b * CDIM + cg * CH)) * NPTS;
    const unsigned short* sp = seg_idx + (size_t)b * NPTS;

    // 65536 points, 256 threads, 4 points/thread/iter -> 64 iterations.
    // Wave reads 1 KB contiguous per channel per iter: fully coalesced.
    for (int it = 0; it < NPTS / (256 * 4); ++it) {
        int p = (it * 256 + tid) * 4;
        ushort4 sg = *reinterpret_cast<const ushort4*>(sp + p);
        float4 fa = *reinterpret_cast<const float4*>(f0 + p);
        float4 fb = *reinterpret_cast<const float4*>(f0 + NPTS + p);
        atomicAdd(&s[sg.x], fa.x);
        atomicAdd(&s[sg.y], fa.y);
        atomicAdd(&s[sg.z], fa.z);
        atomicAdd(&s[sg.w], fa.w);
        atomicAdd(&s[RVOX + sg.x], fb.x);
        atomicAdd(&s[RVOX + sg.y], fb.y);
        atomicAdd(&s[RVOX + sg.z], fb.z);
        atomicAdd(&s[RVOX + sg.w], fb.w);
    }
    __syncthreads();

    // Flush: divide by count, write coalesced float4. RVOX % 4 == 0.
    const int NV = CH * RVOX / 4;                 // 4000 float4s
    for (int i = tid; i < NV; i += 256) {
        int c  = i / (RVOX / 4);
        int rv = i - c * (RVOX / 4);
        float4 v = *reinterpret_cast<float4*>(&s[c * RVOX + rv * 4]);
        int4 h = *reinterpret_cast<const int4*>(&hist[b * RVOX + rv * 4]);
        v.x /= fmaxf((float)h.x, 1.0f);
        v.y /= fmaxf((float)h.y, 1.0f);
        v.z /= fmaxf((float)h.z, 1.0f);
        v.w /= fmaxf((float)h.w, 1.0f);
        float* ob = out + ((size_t)(b * CDIM + cg * CH + c)) * RVOX + rv * 4;
        *reinterpret_cast<float4*>(ob) = v;
    }
}

// ---------- legacy fallback (verified R1) — used only if ws too small -------
__global__ __launch_bounds__(256) void voxel_scatter(
    const float* __restrict__ features, const float* __restrict__ coords,
    const float* __restrict__ search_area, float* __restrict__ sums,
    float* __restrict__ counts)
{
    int gid = blockIdx.x * blockDim.x + threadIdx.x;
    int b = gid >> 16;
    int n = gid & (NPTS - 1);
    const float inv_grid = 1.0f / (float)GRID_D;
    float vsx = search_area[b * 3 + 0] * inv_grid;
    float vsy = search_area[b * 3 + 1] * inv_grid;
    float vsz = search_area[b * 3 + 2] * inv_grid;
    const float* cp = coords + (size_t)b * NPTS * 3 + (size_t)n * 3;
    int ix = (int)(floorf(cp[0] / vsx) + 10.0f);
    int iy = (int)(floorf(cp[1] / vsy) + 10.0f);
    int iz = (int)(floorf(cp[2] / vsz) + 10.0f);
    ix = min(max(ix, 0), GRID_D - 1);
    iy = min(max(iy, 0), GRID_D - 1);
    iz = min(max(iz, 0), GRID_D - 1);
    int flat = ix * (GRID_D * GRID_D) + iy * GRID_D + iz;
    atomicAdd(&counts[b * RVOX + flat], 1.0f);
    const float* fbase = features + (size_t)b * CDIM * NPTS + n;
    float* obase = sums + (size_t)b * CDIM * RVOX + flat;
#pragma unroll 8
    for (int c = 0; c < CDIM; ++c)
        atomicAdd(obase + (size_t)c * RVOX, fbase[(size_t)c * NPTS]);
}

__global__ __launch_bounds__(256) void voxel_finalize(
    float* __restrict__ out, const float* __restrict__ counts)
{
    int gid = blockIdx.x * blockDim.x + threadIdx.x;
    int i = gid * 4;
    int b = i / (CDIM * RVOX);
    int r = i % RVOX;
    float4 s = reinterpret_cast<float4*>(out)[gid];
    float4 cnt = reinterpret_cast<const float4*>(counts)[(b * RVOX + r) >> 2];
    s.x = s.x / fmaxf(cnt.x, 1.0f);
    s.y = s.y / fmaxf(cnt.y, 1.0f);
    s.z = s.z / fmaxf(cnt.z, 1.0f);
    s.w = s.w / fmaxf(cnt.w, 1.0f);
    reinterpret_cast<float4*>(out)[gid] = s;
}

// ---------- launch ----------------------------------------------------------
extern "C" void kernel_launch(void* const* d_in, const int* in_sizes, int n_in,
                              void* d_out, int out_size, void* d_ws, size_t ws_size,
                              hipStream_t stream) {
    const float* features    = (const float*)d_in[0];  // [16, 64, 65536]
    const float* coords      = (const float*)d_in[1];  // [16, 65536, 3]
    const float* search_area = (const float*)d_in[2];  // [16, 3]
    float* out = (float*)d_out;                        // [16, 64, 8000]

    // Workspace layout:
    //   seg_idx: u16[NPT_TOT] @ 0          (2 MB)
    //   hist:    int[NSEG]    @ 2 MB       (512 KB)
    unsigned short* seg_idx = (unsigned short*)d_ws;
    int* hist = (int*)((char*)d_ws + (size_t)NPT_TOT * sizeof(unsigned short));
    size_t need = (size_t)NPT_TOT * 2 + (size_t)NSEG * 4 + 256;

    if (ws_size >= need) {
        hipMemsetAsync(hist, 0, (size_t)NSEG * sizeof(int), stream);
        k_seg<<<NPT_TOT / 256, 256, 0, stream>>>(coords, search_area, seg_idx, hist);
        dim3 agrid(CDIM / CH, BDIM);               // (32, 16) = 512 blocks, 2/CU
        k_accum<<<agrid, 256, 0, stream>>>(features, seg_idx, hist, out);
    } else {
        // Fallback: verified R1 atomic path (needs only 512 KB ws).
        float* counts = (float*)d_ws;
        hipMemsetAsync(out, 0, (size_t)out_size * sizeof(float), stream);
        hipMemsetAsync(counts, 0, (size_t)NSEG * sizeof(float), stream);
        voxel_scatter<<<NPT_TOT / 256, 256, 0, stream>>>(
            features, coords, search_area, out, counts);
        int nvec = (BDIM * CDIM * RVOX) / 4;
        voxel_finalize<<<(nvec + 255) / 256, 256, 0, stream>>>(out, counts);
    }
}

// Round 4
// 634.646 us; speedup vs baseline: 6.1604x; 1.0714x over previous
//
#include <hip/hip_runtime.h>

// Problem constants (fixed by the reference setup_inputs)
#define GRID_D 20
#define RVOX   8000                 // 20^3
#define BDIM   16
#define CDIM   64
#define NPTS   65536
#define NSEG   (BDIM * RVOX)        // 128000
#define NPT_TOT (BDIM * NPTS)       // 1048576

// Native LDS fp32 atomic add, fire-and-forget (no return -> pipelines at
// issue rate instead of the CAS round-trip loop plain atomicAdd can emit).
// `off` is the LDS BYTE offset; dynamic extern __shared__ starts at LDS 0.
__device__ __forceinline__ void lds_fadd(unsigned off, float v) {
    asm volatile("ds_add_f32 %0, %1" :: "v"(off), "v"(v));
}

// ---------- Phase 1: per-point voxel id (u16). NO atomics. ------------------
__global__ __launch_bounds__(256) void k_seg(
    const float* __restrict__ coords, const float* __restrict__ search_area,
    unsigned short* __restrict__ seg_idx)
{
    int gid = blockIdx.x * 256 + threadIdx.x;     // 0 .. NPT_TOT-1
    int b = gid >> 16;
    int n = gid & (NPTS - 1);

    const float inv_grid = 1.0f / (float)GRID_D;
    float vsx = search_area[b * 3 + 0] * inv_grid;
    float vsy = search_area[b * 3 + 1] * inv_grid;
    float vsz = search_area[b * 3 + 2] * inv_grid;
    const float* cp = coords + (size_t)b * NPTS * 3 + (size_t)n * 3;
    int ix = (int)(floorf(cp[0] / vsx) + 10.0f);
    int iy = (int)(floorf(cp[1] / vsy) + 10.0f);
    int iz = (int)(floorf(cp[2] / vsz) + 10.0f);
    ix = min(max(ix, 0), GRID_D - 1);
    iy = min(max(iy, 0), GRID_D - 1);
    iz = min(max(iz, 0), GRID_D - 1);
    seg_idx[gid] = (unsigned short)(ix * (GRID_D * GRID_D) + iy * GRID_D + iz);
}

// ---------- Phase 2: per-batch histogram via native LDS int atomics ---------
// One block per batch element; writes RECIPROCAL counts (flush = multiply).
__global__ __launch_bounds__(256) void k_hist(
    const unsigned short* __restrict__ seg_idx,   // [B, N]
    float* __restrict__ inv_hist)                 // [B, R]
{
    __shared__ int h[RVOX];                       // 32 KB
    int b = blockIdx.x;
    int tid = threadIdx.x;
    for (int i = tid; i < RVOX; i += 256) h[i] = 0;
    __syncthreads();

    const unsigned short* sp = seg_idx + (size_t)b * NPTS;
    for (int it = 0; it < NPTS / (256 * 4); ++it) {
        ushort4 sg = *reinterpret_cast<const ushort4*>(sp + (it * 256 + tid) * 4);
        atomicAdd(&h[sg.x], 1);                   // int LDS atomics are native
        atomicAdd(&h[sg.y], 1);
        atomicAdd(&h[sg.z], 1);
        atomicAdd(&h[sg.w], 1);
    }
    __syncthreads();
    for (int i = tid; i < RVOX; i += 256)
        inv_hist[b * RVOX + i] = 1.0f / (float)max(h[i], 1);
}

// ---------- Phase 3: LDS-accumulated segment sum + fused mean ---------------
// Block = (channel c, batch b). 32 KB dynamic LDS -> 4 blocks/CU (16 waves).
// Streams 65536 points: coalesced float4 feature + ushort4 seg loads with a
// 1-iter software prefetch; native ds_add_f32 into LDS; coalesced float4
// flush multiplied by 1/count. Features read exactly once; no global atomics.
__global__ __launch_bounds__(256) void k_accum(
    const float* __restrict__ features,           // [B, C, N]
    const unsigned short* __restrict__ seg_idx,   // [B, N]
    const float* __restrict__ inv_hist,           // [B, R]
    float* __restrict__ out)                      // [B, C, R]
{
    extern __shared__ float s[];                  // RVOX floats, LDS offset 0
    int tid = threadIdx.x;
    int c = blockIdx.x;                           // 0 .. 63
    int b = blockIdx.y;                           // 0 .. 15

    for (int i = tid; i < RVOX; i += 256) s[i] = 0.0f;
    __syncthreads();

    const float* f0 = features + ((size_t)(b * CDIM + c)) * NPTS;
    const unsigned short* sp = seg_idx + (size_t)b * NPTS;

    const int ITER = NPTS / (256 * 4);            // 64
    int p = tid * 4;
    ushort4 sg = *reinterpret_cast<const ushort4*>(sp + p);
    float4  f  = *reinterpret_cast<const float4*>(f0 + p);
    for (int it = 0; it < ITER; ++it) {
        ushort4 sgn = sg;
        float4  fn  = f;
        int pn = p + 1024;
        if (it + 1 < ITER) {                      // prefetch next iteration
            sgn = *reinterpret_cast<const ushort4*>(sp + pn);
            fn  = *reinterpret_cast<const float4*>(f0 + pn);
        }
        lds_fadd((unsigned)(sg.x * 4), f.x);
        lds_fadd((unsigned)(sg.y * 4), f.y);
        lds_fadd((unsigned)(sg.z * 4), f.z);
        lds_fadd((unsigned)(sg.w * 4), f.w);
        sg = sgn; f = fn; p = pn;
    }
    // Drain this wave's DS ops (compiler doesn't track the asm), then barrier.
    asm volatile("s_waitcnt lgkmcnt(0)");
    __syncthreads();

    const float* ih = inv_hist + b * RVOX;
    float* ob = out + ((size_t)(b * CDIM + c)) * RVOX;
    for (int i = tid; i < RVOX / 4; i += 256) {
        float4 v = *reinterpret_cast<float4*>(&s[i * 4]);
        float4 w = *reinterpret_cast<const float4*>(&ih[i * 4]);
        v.x *= w.x; v.y *= w.y; v.z *= w.z; v.w *= w.w;
        *reinterpret_cast<float4*>(ob + i * 4) = v;
    }
}

// ---------- legacy fallback (verified R1) — used only if ws too small -------
__global__ __launch_bounds__(256) void voxel_scatter(
    const float* __restrict__ features, const float* __restrict__ coords,
    const float* __restrict__ search_area, float* __restrict__ sums,
    float* __restrict__ counts)
{
    int gid = blockIdx.x * blockDim.x + threadIdx.x;
    int b = gid >> 16;
    int n = gid & (NPTS - 1);
    const float inv_grid = 1.0f / (float)GRID_D;
    float vsx = search_area[b * 3 + 0] * inv_grid;
    float vsy = search_area[b * 3 + 1] * inv_grid;
    float vsz = search_area[b * 3 + 2] * inv_grid;
    const float* cp = coords + (size_t)b * NPTS * 3 + (size_t)n * 3;
    int ix = (int)(floorf(cp[0] / vsx) + 10.0f);
    int iy = (int)(floorf(cp[1] / vsy) + 10.0f);
    int iz = (int)(floorf(cp[2] / vsz) + 10.0f);
    ix = min(max(ix, 0), GRID_D - 1);
    iy = min(max(iy, 0), GRID_D - 1);
    iz = min(max(iz, 0), GRID_D - 1);
    int flat = ix * (GRID_D * GRID_D) + iy * GRID_D + iz;
    atomicAdd(&counts[b * RVOX + flat], 1.0f);
    const float* fbase = features + (size_t)b * CDIM * NPTS + n;
    float* obase = sums + (size_t)b * CDIM * RVOX + flat;
#pragma unroll 8
    for (int c = 0; c < CDIM; ++c)
        atomicAdd(obase + (size_t)c * RVOX, fbase[(size_t)c * NPTS]);
}

__global__ __launch_bounds__(256) void voxel_finalize(
    float* __restrict__ out, const float* __restrict__ counts)
{
    int gid = blockIdx.x * blockDim.x + threadIdx.x;
    int i = gid * 4;
    int b = i / (CDIM * RVOX);
    int r = i % RVOX;
    float4 s = reinterpret_cast<float4*>(out)[gid];
    float4 cnt = reinterpret_cast<const float4*>(counts)[(b * RVOX + r) >> 2];
    s.x = s.x / fmaxf(cnt.x, 1.0f);
    s.y = s.y / fmaxf(cnt.y, 1.0f);
    s.z = s.z / fmaxf(cnt.z, 1.0f);
    s.w = s.w / fmaxf(cnt.w, 1.0f);
    reinterpret_cast<float4*>(out)[gid] = s;
}

// ---------- launch ----------------------------------------------------------
extern "C" void kernel_launch(void* const* d_in, const int* in_sizes, int n_in,
                              void* d_out, int out_size, void* d_ws, size_t ws_size,
                              hipStream_t stream) {
    const float* features    = (const float*)d_in[0];  // [16, 64, 65536]
    const float* coords      = (const float*)d_in[1];  // [16, 65536, 3]
    const float* search_area = (const float*)d_in[2];  // [16, 3]
    float* out = (float*)d_out;                        // [16, 64, 8000]

    // Workspace: seg_idx u16[NPT_TOT] (2 MB) + inv_hist f32[NSEG] (512 KB)
    unsigned short* seg_idx = (unsigned short*)d_ws;
    float* inv_hist = (float*)((char*)d_ws + (size_t)NPT_TOT * sizeof(unsigned short));
    size_t need = (size_t)NPT_TOT * 2 + (size_t)NSEG * 4 + 256;

    if (ws_size >= need) {
        k_seg<<<NPT_TOT / 256, 256, 0, stream>>>(coords, search_area, seg_idx);
        k_hist<<<BDIM, 256, 0, stream>>>(seg_idx, inv_hist);
        dim3 agrid(CDIM, BDIM);                    // 1024 blocks, 4/CU (32KB LDS)
        k_accum<<<agrid, 256, RVOX * sizeof(float), stream>>>(
            features, seg_idx, inv_hist, out);
    } else {
        // Fallback: verified R1 atomic path (needs only 512 KB ws).
        float* counts = (float*)d_ws;
        hipMemsetAsync(out, 0, (size_t)out_size * sizeof(float), stream);
        hipMemsetAsync(counts, 0, (size_t)NSEG * sizeof(float), stream);
        voxel_scatter<<<NPT_TOT / 256, 256, 0, stream>>>(
            features, coords, search_area, out, counts);
        int nvec = (BDIM * CDIM * RVOX) / 4;
        voxel_finalize<<<(nvec + 255) / 256, 256, 0, stream>>>(out, counts);
    }
}